// Round 10
// baseline (416.049 us; speedup 1.0000x reference)
//
#include <hip/hip_runtime.h>
#include <stdint.h>

using fx4   = __attribute__((ext_vector_type(4))) float;
using half8 = __attribute__((ext_vector_type(8))) _Float16;

__device__ __forceinline__ ushort f2h(float x) {
  _Float16 h = (_Float16)x;
  union { _Float16 hv; ushort u; } v; v.hv = h;
  return v.u;
}

__device__ __forceinline__ void gload_lds16(const ushort* g, ushort* l) {
  __builtin_amdgcn_global_load_lds(
      (__attribute__((address_space(1))) const void*)g,
      (__attribute__((address_space(3))) void*)l, 16, 0, 0);
}

#define MFMA16(a, b, c) __builtin_amdgcn_mfma_f32_16x16x32_f16(a, b, c, 0, 0, 0)

// Shared GEMM body. C[m][n] = sum_k A[m][k]*B[n][k] (B transposed, fp16, fp32 acc)
// flags: 1=relu, 2=store fp16 row-major,
//        16 = swizzled V-panel store (VT layout [panel][512 d][32 tok])
//        32 = swizzled KT panels (col<256) + Qm row-major (col>=256, via C2)
__device__ __forceinline__ void gemm_body(
    const ushort* __restrict__ A, int lda,
    const ushort* __restrict__ B, int ldb,
    const float* __restrict__ bias,
    void* __restrict__ C, int ldc,
    int K, int flags, int bx, int by,
    ushort* As, ushort* Bs, ushort* __restrict__ C2 = nullptr)
{
  const int tid  = threadIdx.x;
  const int lane = tid & 63;
  const int wave = tid >> 6;
  const int wm   = (wave >> 1) * 64;
  const int wn   = (wave & 1) * 64;
  const long long bm = (long long)by * 128;
  const long long bn = (long long)bx * 128;

  const int srow = tid >> 2;
  const int skq  = (tid & 3) * 8;
  const ushort* a0 = A + (bm + srow) * lda + skq;
  const ushort* a1 = a0 + 64LL * lda;
  const ushort* b0 = B + (bn + srow) * ldb + skq;
  const ushort* b1 = b0 + 64LL * ldb;
  ushort* lA0 = &As[tid * 8];
  ushort* lA1 = &As[2048 + tid * 8];
  ushort* lB0 = &Bs[tid * 8];
  ushort* lB1 = &Bs[2048 + tid * 8];

  fx4 acc[4][4] = {};
  const ushort* ap = &As[(wm + (lane & 15)) * 32 + (lane >> 4) * 8];
  const ushort* bp = &Bs[(wn + (lane & 15)) * 32 + (lane >> 4) * 8];

  for (int k0 = 0; k0 < K; k0 += 32) {
    gload_lds16(a0, lA0);
    gload_lds16(a1, lA1);
    gload_lds16(b0, lB0);
    gload_lds16(b1, lB1);
    a0 += 32; a1 += 32; b0 += 32; b1 += 32;
    __syncthreads();
    half8 af[4], bv[4];
#pragma unroll
    for (int t = 0; t < 4; ++t) {
      af[t] = *(const half8*)(ap + t * 16 * 32);
      bv[t] = *(const half8*)(bp + t * 16 * 32);
    }
#pragma unroll
    for (int i = 0; i < 4; ++i)
#pragma unroll
      for (int j = 0; j < 4; ++j)
        acc[i][j] = MFMA16(af[i], bv[j], acc[i][j]);
    __syncthreads();
  }

  const int col0 = (int)bn + wn + (lane & 15);
  const int row0 = (int)bm + wm + ((lane >> 4) << 2);

  if (flags & 16) {        // VT panel store, swizzled: rows=tok, cols=d
    ushort* Ch = (ushort*)C;
#pragma unroll
    for (int j = 0; j < 4; ++j) {
      const int col = col0 + j * 16;
      const float bvv = bias ? bias[col] : 0.0f;
      const int key = (col ^ (col >> 2)) & 3;
#pragma unroll
      for (int i = 0; i < 4; ++i) {
        const int row = row0 + i * 16;
        const int g = (row & 31) >> 3;
        ushort4 o;
        o.x = f2h(acc[i][j][0] + bvv);
        o.y = f2h(acc[i][j][1] + bvv);
        o.z = f2h(acc[i][j][2] + bvv);
        o.w = f2h(acc[i][j][3] + bvv);
        *(ushort4*)(Ch + (long long)(row >> 5) * 16384 + (long long)col * 32 +
                    ((g ^ key) << 3) + (row & 7)) = o;
      }
    }
    return;
  }

  if (flags & 32) {        // KT panels (swizzled) + Qm split
    ushort* KTp = (ushort*)C;
#pragma unroll
    for (int j = 0; j < 4; ++j) {
      const int col = col0 + j * 16;
      const float bvv = bias ? bias[col] : 0.0f;
#pragma unroll
      for (int i = 0; i < 4; ++i) {
        const int row = row0 + i * 16;
#pragma unroll
        for (int r = 0; r < 4; ++r) {
          const float v = acc[i][j][r] + bvv;
          if (col < 256) {
            const int tok = row + r;
            const int key = (tok ^ (tok >> 2)) & 3;
            const int dp  = col & 31;
            KTp[(long long)(tok >> 5) * 8192 + (col >> 5) * 1024 +
                (tok & 31) * 32 + (((dp >> 3) ^ key) << 3) + (dp & 7)] = f2h(v);
          } else {
            C2[(long long)(row + r) * 256 + (col - 256)] = f2h(v);
          }
        }
      }
    }
    return;
  }

  float*  Cf = (float*)C;
  ushort* Ch = (ushort*)C;
#pragma unroll
  for (int j = 0; j < 4; ++j) {
    const int col = col0 + j * 16;
    const float bvv = bias ? bias[col] : 0.0f;
#pragma unroll
    for (int i = 0; i < 4; ++i) {
      const long long row = row0 + i * 16;
#pragma unroll
      for (int r = 0; r < 4; ++r) {
        float v = acc[i][j][r] + bvv;
        if (flags & 1) v = fmaxf(v, 0.0f);
        if (flags & 2) Ch[(row + r) * ldc + col] = f2h(v);
        else           Cf[(row + r) * ldc + col] = v;
      }
    }
  }
}

__global__ __launch_bounds__(256)
void gemm_bt(const ushort* __restrict__ A, int lda, long long sA,
             const ushort* __restrict__ B, int ldb, long long sB,
             const float* __restrict__ bias,
             void* __restrict__ C, int ldc, long long sC,
             int K, int flags)
{
  __shared__ ushort As[128 * 32];
  __shared__ ushort Bs[128 * 32];
  const int z = blockIdx.z;
  void* Cz = (flags & 2) ? (void*)((ushort*)C + (long long)z * sC)
                         : (void*)((float*)C + (long long)z * sC);
  gemm_body(A + (long long)z * sA, lda, B + (long long)z * sB, ldb, bias,
            Cz, ldc, K, flags, blockIdx.x, blockIdx.y, As, Bs);
}

// z=0: VT panels = (H[:,:1024] @ We2 + be2)  ; z=1: KT panels + Qm
__global__ __launch_bounds__(256)
void gemm2_pair(const ushort* __restrict__ H, const ushort* __restrict__ W2c,
                const float* __restrict__ be2, const float* __restrict__ bk2,
                ushort* __restrict__ VT, ushort* __restrict__ KT,
                ushort* __restrict__ Qm)
{
  __shared__ ushort As[128 * 32];
  __shared__ ushort Bs[128 * 32];
  if (blockIdx.z == 0)
    gemm_body(H, 2048, W2c, 1024, be2, VT, 0, 1024, 16,
              blockIdx.x, blockIdx.y, As, Bs);
  else
    gemm_body(H + 1024, 2048, W2c + 524288, 1024, bk2, KT, 0, 1024, 32,
              blockIdx.x, blockIdx.y, As, Bs, Qm);
}

// Flash attention. Block = (batch, 32-q tile), 256 thr / 4 waves; wave = all
// 32 q x 128-d slice (dh = w*128). QK duplicated x4 (Q in regs) -> softmax is
// fully wave-local, zero mid-tile barriers. K/V staged single-buffered via
// contiguous global_load_lds from swizzled panels (conflict-free frag reads).
// 2 barriers/tile; LDS 58 KB; grid 512 -> 2 blocks/CU (barrier-drain overlap).
__global__ __launch_bounds__(256, 2)
void attn_fused(const ushort* __restrict__ KT, const ushort* __restrict__ VT,
                const ushort* __restrict__ Qm, float* __restrict__ out)
{
  __shared__ ushort Ks[8192];      // [dc 8][tok 32][32 d] swizzled   16 KB
  __shared__ ushort Vs[16384];     // [d 512][tok 32] swizzled        32 KB
  __shared__ ushort Ps[4][1280];   // per-wave [q 32][40]             10 KB

  const int tid  = threadIdx.x;
  const int lane = tid & 63;
  const int w    = tid >> 6;
  const int c    = lane & 15;
  const int quad = lane >> 4;
  const int dh   = w << 7;               // wave's 128-d slice
  const int z    = blockIdx.x;           // batch; blkid%8 = batch -> XCD-pinned
  const long long tb = (long long)z * 2048;
  const int q0   = blockIdx.y * 32;

  ushort* Pw = Ps[w];

  // Q a-frags in registers: 32 q x 256 d (16 half8 = 64 VGPR)
  half8 qa[2][8];
#pragma unroll
  for (int qi = 0; qi < 2; ++qi)
#pragma unroll
    for (int dc = 0; dc < 8; ++dc)
      qa[qi][dc] = *(const half8*)(Qm + (tb + q0 + qi * 16 + c) * 256 +
                                   dc * 32 + quad * 8);

  float m_[2][4], l_[2][4];
#pragma unroll
  for (int qi = 0; qi < 2; ++qi)
#pragma unroll
    for (int r = 0; r < 4; ++r) { m_[qi][r] = -3.0e38f; l_[qi][r] = 0.0f; }
  fx4 o[2][8] = {};

  const long long pbase = tb >> 5;       // first panel of this batch
  {
    const ushort* ksrc = KT + pbase * 8192;
    const ushort* vsrc = VT + pbase * 16384;
#pragma unroll
    for (int i = 0; i < 4; ++i) { const int u = i * 256 + tid; gload_lds16(ksrc + u * 8, Ks + u * 8); }
#pragma unroll
    for (int i = 0; i < 8; ++i) { const int u = i * 256 + tid; gload_lds16(vsrc + u * 8, Vs + u * 8); }
  }

  const int keyA = (c ^ (c >> 2)) & 3;
  const int keyB = ((c + 16) ^ ((c + 16) >> 2)) & 3;

  for (int t = 0; t < 64; ++t) {
    __syncthreads();                     // DMA(t) drained; prior readers done

    // ---- QK: S[2 qi][2 tj] over d=256 ----
    fx4 s[2][2] = {};
#pragma unroll
    for (int dc = 0; dc < 8; ++dc) {
      const half8 b0 = *(const half8*)(Ks + dc * 1024 + c * 32 + ((quad ^ keyA) << 3));
      const half8 b1 = *(const half8*)(Ks + dc * 1024 + (16 + c) * 32 + ((quad ^ keyB) << 3));
      s[0][0] = MFMA16(qa[0][dc], b0, s[0][0]); s[0][1] = MFMA16(qa[0][dc], b1, s[0][1]);
      s[1][0] = MFMA16(qa[1][dc], b0, s[1][0]); s[1][1] = MFMA16(qa[1][dc], b1, s[1][1]);
    }

    // ---- wave-local online softmax (rows q = qi*16 + quad*4 + r) ----
#pragma unroll
    for (int qi = 0; qi < 2; ++qi) {
      fx4 rm;
#pragma unroll
      for (int r = 0; r < 4; ++r) rm[r] = fmaxf(s[qi][0][r], s[qi][1][r]);
#pragma unroll
      for (int off = 1; off < 16; off <<= 1)
#pragma unroll
        for (int r = 0; r < 4; ++r) rm[r] = fmaxf(rm[r], __shfl_xor(rm[r], off, 64));
      float alpha[4];
#pragma unroll
      for (int r = 0; r < 4; ++r) {
        const float mn = fmaxf(m_[qi][r], rm[r]);
        alpha[r] = __expf(m_[qi][r] - mn);
        m_[qi][r] = mn;
        const float e0 = __expf(s[qi][0][r] - mn);
        const float e1 = __expf(s[qi][1][r] - mn);
        l_[qi][r] = alpha[r] * l_[qi][r] + e0 + e1;   // per-lane partial (c-slice)
        Pw[(qi * 16 + quad * 4 + r) * 40 + c]      = f2h(e0);
        Pw[(qi * 16 + quad * 4 + r) * 40 + 16 + c] = f2h(e1);
      }
#pragma unroll
      for (int n = 0; n < 8; ++n)
#pragma unroll
        for (int r = 0; r < 4; ++r) o[qi][n][r] *= alpha[r];
    }

    // ---- PV: pa wave-private (lgkmcnt only), vb from swizzled Vs ----
    const half8 pa0 = *(const half8*)(Pw + c * 40 + quad * 8);
    const half8 pa1 = *(const half8*)(Pw + (16 + c) * 40 + quad * 8);
#pragma unroll
    for (int n = 0; n < 8; ++n) {
      const int d = dh + n * 16 + c;
      const int vkey = (d ^ (d >> 2)) & 3;
      const half8 vb = *(const half8*)(Vs + d * 32 + ((quad ^ vkey) << 3));
      o[0][n] = MFMA16(pa0, vb, o[0][n]);
      o[1][n] = MFMA16(pa1, vb, o[1][n]);
    }

    __syncthreads();                     // all waves done reading Ks/Vs
    if (t < 63) {                        // stage next tile (drain overlaps other block)
      const ushort* ksrc = KT + (pbase + t + 1) * 8192;
      const ushort* vsrc = VT + (pbase + t + 1) * 16384;
#pragma unroll
      for (int i = 0; i < 4; ++i) { const int u = i * 256 + tid; gload_lds16(ksrc + u * 8, Ks + u * 8); }
#pragma unroll
      for (int i = 0; i < 8; ++i) { const int u = i * 256 + tid; gload_lds16(vsrc + u * 8, Vs + u * 8); }
    }
  }

  // ---- epilogue: reduce l over 16-lane token slices, normalize, store ----
#pragma unroll
  for (int qi = 0; qi < 2; ++qi) {
    fx4 lv;
#pragma unroll
    for (int r = 0; r < 4; ++r) lv[r] = l_[qi][r];
#pragma unroll
    for (int off = 1; off < 16; off <<= 1)
#pragma unroll
      for (int r = 0; r < 4; ++r) lv[r] += __shfl_xor(lv[r], off, 64);
#pragma unroll
    for (int r = 0; r < 4; ++r) {
      const float linv = 1.0f / lv[r];
      const long long row = tb + q0 + qi * 16 + quad * 4 + r;
#pragma unroll
      for (int n = 0; n < 8; ++n)
        out[row * 512 + dh + n * 16 + c] = o[qi][n][r] * linv;
    }
  }
}

// fp32 [R][C] -> fp16 [C][R], two inputs selected by blockIdx.z
__global__ __launch_bounds__(256)
void transpose_cast_w2(const float* __restrict__ in0, const float* __restrict__ in1,
                       ushort* __restrict__ out0, ushort* __restrict__ out1,
                       int R, int C) {
  __shared__ float tile[32][33];
  const float* in  = blockIdx.z ? in1 : in0;
  ushort*      outp = blockIdx.z ? out1 : out0;
  const int c0 = blockIdx.x * 32, r0 = blockIdx.y * 32;
  const int tx = threadIdx.x & 31, ty = threadIdx.x >> 5;
#pragma unroll
  for (int i = 0; i < 32; i += 8)
    tile[ty + i][tx] = in[(long long)(r0 + ty + i) * C + (c0 + tx)];
  __syncthreads();
#pragma unroll
  for (int i = 0; i < 32; i += 8)
    outp[(long long)(c0 + ty + i) * R + (r0 + tx)] = f2h(tile[tx][ty + i]);
}

__global__ __launch_bounds__(256)
void cast_f32_f16(const float* __restrict__ in, ushort* __restrict__ out) {
  const long long i = ((long long)blockIdx.x * 256 + threadIdx.x) * 4;
  const float4 v = *(const float4*)(in + i);
  ushort4 o;
  o.x = f2h(v.x); o.y = f2h(v.y); o.z = f2h(v.z); o.w = f2h(v.w);
  *(ushort4*)(out + i) = o;
}

__global__ __launch_bounds__(256)
void concat_bias(const float* __restrict__ b0, const float* __restrict__ b1,
                 float* __restrict__ out) {
  const int i = blockIdx.x * 256 + threadIdx.x;
  out[i] = (i < 1024) ? b0[i] : b1[i - 1024];
}

extern "C" void kernel_launch(void* const* d_in, const int* in_sizes, int n_in,
                              void* d_out, int out_size, void* d_ws, size_t ws_size,
                              hipStream_t stream) {
  (void)in_sizes; (void)n_in; (void)out_size; (void)ws_size;
  const float* x   = (const float*)d_in[0];
  const float* We1 = (const float*)d_in[1];
  const float* be1 = (const float*)d_in[2];
  const float* We2 = (const float*)d_in[3];
  const float* be2 = (const float*)d_in[4];
  const float* Wk1 = (const float*)d_in[5];
  const float* bk1 = (const float*)d_in[6];
  const float* Wk2 = (const float*)d_in[7];
  const float* bk2 = (const float*)d_in[8];
  float* out = (float*)d_out;
  char* ws = (char*)d_ws;

  ushort* Xb  = (ushort*)(ws + 0);            // 16.78 MB, dead after gemm1
  ushort* W2c = (ushort*)(ws + 0);            // 2 MB, written after gemm1
  ushort* H   = (ushort*)(ws + 16777216);     // 16384x2048 fp16 = 67.1 MB
  ushort* VT  = (ushort*)(ws + 83886080);     // 512 panels x [512][32] = 16.78 MB
  ushort* KT  = (ushort*)(ws + 100663296);    // 512 panels x [8][32][32] = 8.39 MB
  ushort* Qm  = (ushort*)(ws + 109051904);    // 16384x256 fp16 = 8.39 MB
  float*  b1c = (float*)(ws + 117440512);     // 2048 fp32
  ushort* W1c = (ushort*)(ws + 117448704);    // 2 MB

  cast_f32_f16<<<dim3(8192), 256, 0, stream>>>(x, Xb);
  transpose_cast_w2<<<dim3(32, 16, 2), 256, 0, stream>>>(We1, Wk1, W1c, W1c + 524288, 512, 1024);
  concat_bias<<<dim3(8), 256, 0, stream>>>(be1, bk1, b1c);

  // H = relu(x @ [We1|Wk1] + [be1|bk1])   [16384,2048]
  gemm_bt<<<dim3(16, 128, 1), 256, 0, stream>>>(Xb, 512, 0, W1c, 512, 0, b1c,
                                                H, 2048, 0, 512, 1 | 2);

  transpose_cast_w2<<<dim3(16, 32, 2), 256, 0, stream>>>(We2, Wk2, W2c, W2c + 524288, 1024, 512);

  // z=0: VT panels (swizzled) ; z=1: KT panels (swizzled) + Qm
  gemm2_pair<<<dim3(4, 128, 2), 256, 0, stream>>>(H, W2c, be2, bk2, VT, KT, Qm);

  // flash attention: grid x=batch (XCD-pinned), y=32-q tile -> 512 blocks, 2/CU
  attn_fused<<<dim3(8, 64), 256, 0, stream>>>(KT, VT, Qm, out);
}

// Round 11
// 314.809 us; speedup vs baseline: 1.3216x; 1.3216x over previous
//
#include <hip/hip_runtime.h>
#include <stdint.h>

using fx4   = __attribute__((ext_vector_type(4))) float;
using half8 = __attribute__((ext_vector_type(8))) _Float16;

__device__ __forceinline__ ushort f2h(float x) {
  _Float16 h = (_Float16)x;
  union { _Float16 hv; ushort u; } v; v.hv = h;
  return v.u;
}

__device__ __forceinline__ void gload_lds16(const ushort* g, ushort* l) {
  __builtin_amdgcn_global_load_lds(
      (__attribute__((address_space(1))) const void*)g,
      (__attribute__((address_space(3))) void*)l, 16, 0, 0);
}

#define MFMA16(a, b, c) __builtin_amdgcn_mfma_f32_16x16x32_f16(a, b, c, 0, 0, 0)

// Shared GEMM body. C[m][n] = sum_k A[m][k]*B[n][k] (B transposed, fp16, fp32 acc)
// flags: 1=relu, 2=store fp16 row-major,
//        16 = V-panel store: VT[(row>>5)*16384 + col*32 + (row&31)]
//        32 = KT panels (col<256) + Qm row-major (col>=256, via C2)
__device__ __forceinline__ void gemm_body(
    const ushort* __restrict__ A, int lda,
    const ushort* __restrict__ B, int ldb,
    const float* __restrict__ bias,
    void* __restrict__ C, int ldc,
    int K, int flags, int bx, int by,
    ushort* As, ushort* Bs, ushort* __restrict__ C2 = nullptr)
{
  const int tid  = threadIdx.x;
  const int lane = tid & 63;
  const int wave = tid >> 6;
  const int wm   = (wave >> 1) * 64;
  const int wn   = (wave & 1) * 64;
  const long long bm = (long long)by * 128;
  const long long bn = (long long)bx * 128;

  const int srow = tid >> 2;
  const int skq  = (tid & 3) * 8;
  const ushort* a0 = A + (bm + srow) * lda + skq;
  const ushort* a1 = a0 + 64LL * lda;
  const ushort* b0 = B + (bn + srow) * ldb + skq;
  const ushort* b1 = b0 + 64LL * ldb;
  ushort* lA0 = &As[tid * 8];
  ushort* lA1 = &As[2048 + tid * 8];
  ushort* lB0 = &Bs[tid * 8];
  ushort* lB1 = &Bs[2048 + tid * 8];

  fx4 acc[4][4] = {};
  const ushort* ap = &As[(wm + (lane & 15)) * 32 + (lane >> 4) * 8];
  const ushort* bp = &Bs[(wn + (lane & 15)) * 32 + (lane >> 4) * 8];

  for (int k0 = 0; k0 < K; k0 += 32) {
    gload_lds16(a0, lA0);
    gload_lds16(a1, lA1);
    gload_lds16(b0, lB0);
    gload_lds16(b1, lB1);
    a0 += 32; a1 += 32; b0 += 32; b1 += 32;
    __syncthreads();
    half8 af[4], bv[4];
#pragma unroll
    for (int t = 0; t < 4; ++t) {
      af[t] = *(const half8*)(ap + t * 16 * 32);
      bv[t] = *(const half8*)(bp + t * 16 * 32);
    }
#pragma unroll
    for (int i = 0; i < 4; ++i)
#pragma unroll
      for (int j = 0; j < 4; ++j)
        acc[i][j] = MFMA16(af[i], bv[j], acc[i][j]);
    __syncthreads();
  }

  const int col0 = (int)bn + wn + (lane & 15);
  const int row0 = (int)bm + wm + ((lane >> 4) << 2);

  if (flags & 16) {        // VT panel store: [panel][d 512][tok 32]
    ushort* Ch = (ushort*)C;
#pragma unroll
    for (int j = 0; j < 4; ++j) {
      const int col = col0 + j * 16;
      const float bvv = bias ? bias[col] : 0.0f;
#pragma unroll
      for (int i = 0; i < 4; ++i) {
        const int row = row0 + i * 16;
        ushort4 o;
        o.x = f2h(acc[i][j][0] + bvv);
        o.y = f2h(acc[i][j][1] + bvv);
        o.z = f2h(acc[i][j][2] + bvv);
        o.w = f2h(acc[i][j][3] + bvv);
        *(ushort4*)(Ch + (long long)(row >> 5) * 16384 + (long long)col * 32 + (row & 31)) = o;
      }
    }
    return;
  }

  if (flags & 32) {        // KT panels [p][dc 8][tok 32][32] + Qm row-major
    ushort* KTp = (ushort*)C;
#pragma unroll
    for (int j = 0; j < 4; ++j) {
      const int col = col0 + j * 16;
      const float bvv = bias ? bias[col] : 0.0f;
#pragma unroll
      for (int i = 0; i < 4; ++i) {
        const int row = row0 + i * 16;
#pragma unroll
        for (int r = 0; r < 4; ++r) {
          const float v = acc[i][j][r] + bvv;
          if (col < 256) {
            const int tok = row + r;
            KTp[(long long)(tok >> 5) * 8192 + (col >> 5) * 1024 +
                (tok & 31) * 32 + (col & 31)] = f2h(v);
          } else {
            C2[(long long)(row + r) * 256 + (col - 256)] = f2h(v);
          }
        }
      }
    }
    return;
  }

  float*  Cf = (float*)C;
  ushort* Ch = (ushort*)C;
#pragma unroll
  for (int j = 0; j < 4; ++j) {
    const int col = col0 + j * 16;
    const float bvv = bias ? bias[col] : 0.0f;
#pragma unroll
    for (int i = 0; i < 4; ++i) {
      const long long row = row0 + i * 16;
#pragma unroll
      for (int r = 0; r < 4; ++r) {
        float v = acc[i][j][r] + bvv;
        if (flags & 1) v = fmaxf(v, 0.0f);
        if (flags & 2) Ch[(row + r) * ldc + col] = f2h(v);
        else           Cf[(row + r) * ldc + col] = v;
      }
    }
  }
}

__global__ __launch_bounds__(256)
void gemm_bt(const ushort* __restrict__ A, int lda, long long sA,
             const ushort* __restrict__ B, int ldb, long long sB,
             const float* __restrict__ bias,
             void* __restrict__ C, int ldc, long long sC,
             int K, int flags)
{
  __shared__ ushort As[128 * 32];
  __shared__ ushort Bs[128 * 32];
  const int z = blockIdx.z;
  void* Cz = (flags & 2) ? (void*)((ushort*)C + (long long)z * sC)
                         : (void*)((float*)C + (long long)z * sC);
  gemm_body(A + (long long)z * sA, lda, B + (long long)z * sB, ldb, bias,
            Cz, ldc, K, flags, blockIdx.x, blockIdx.y, As, Bs);
}

// z=0: VT panels = (H[:,:1024] @ We2 + be2)  ; z=1: KT panels + Qm
__global__ __launch_bounds__(256)
void gemm2_pair(const ushort* __restrict__ H, const ushort* __restrict__ W2c,
                const float* __restrict__ be2, const float* __restrict__ bk2,
                ushort* __restrict__ VT, ushort* __restrict__ KT,
                ushort* __restrict__ Qm)
{
  __shared__ ushort As[128 * 32];
  __shared__ ushort Bs[128 * 32];
  if (blockIdx.z == 0)
    gemm_body(H, 2048, W2c, 1024, be2, VT, 0, 1024, 16,
              blockIdx.x, blockIdx.y, As, Bs);
  else
    gemm_body(H + 1024, 2048, W2c + 524288, 1024, bk2, KT, 0, 1024, 32,
              blockIdx.x, blockIdx.y, As, Bs, Qm);
}

// Single-pass flash attention (the 147-us skeleton), with K/V frag loads from
// panel layouts: every load is a contiguous 1 KB per instruction (lane offset
// = c*64 + q4*16 bytes) instead of 16 quarter-used cache-line gathers.
// Block = (batch, 64-q tile), 512 thr / 8 waves. QK: wave (qw 2 x tw 4) does
// a 32q x 32tok S subtile; PV: wave w owns d-slice [w*64, w*64+64).
__global__ __launch_bounds__(512, 2)
void attn_fused(const ushort* __restrict__ KT, const ushort* __restrict__ VT,
                const ushort* __restrict__ Qm, float* __restrict__ out)
{
  __shared__ ushort Qs[20480];   // [dc 8][64 q][40]
  __shared__ ushort Ps[10240];   // [kc 4][64 q][40]
  __shared__ float  rmax[256];   // [tw 4][64 q]
  __shared__ float  mstate[64];
  __shared__ float  mnewA[64];
  __shared__ float  alphaA[64];  // reused as linv in epilogue
  __shared__ float  lred[256];   // [tw 4][64 q]

  const int tid  = threadIdx.x;
  const int lane = tid & 63;
  const int w    = tid >> 6;
  const int c    = lane & 15;
  const int q4   = lane >> 4;
  const int qw   = w >> 2;       // 0..1
  const int tw   = w & 3;        // 0..3
  const int dw   = w * 64;       // d-slice base
  const int z    = blockIdx.x;   // batch -> XCD locality
  const long long tb = (long long)z * 2048;
  const long long pbase = (long long)z * 64;   // first 32-tok panel of batch
  const int q0   = blockIdx.y * 64;

  // stage Q-tile 64x256 into padded LDS from Qm
#pragma unroll
  for (int p = 0; p < 4; ++p) {
    const int cu  = p * 512 + tid;       // 0..2047
    const int row = cu >> 5;             // 0..63
    const int kch = cu & 31;
    const int dc  = kch >> 2, qg = kch & 3;
    const half8 v = *(const half8*)(Qm + (tb + q0 + row) * 256 + dc * 32 + qg * 8);
    *(half8*)(Qs + dc * 2560 + row * 40 + qg * 8) = v;
  }
  if (tid < 64) mstate[tid] = -3.0e38f;
  __syncthreads();

  float l_part[2][4] = {};
  fx4 o[4][4] = {};

  for (int t0 = 0; t0 < 2048; t0 += 128) {
    const long long pt = pbase + (t0 >> 5);
    // ---- hoist all 16 K b-frags (coalesced panel loads), then QK MFMAs ----
    half8 kb[2][8];
    const ushort* kp = KT + (pt + tw) * 8192;
#pragma unroll
    for (int dc = 0; dc < 8; ++dc) {
      kb[0][dc] = *(const half8*)(kp + dc * 1024 + c * 32 + q4 * 8);
      kb[1][dc] = *(const half8*)(kp + dc * 1024 + (16 + c) * 32 + q4 * 8);
    }
    fx4 s[2][2] = {};
#pragma unroll
    for (int dc = 0; dc < 8; ++dc) {
      const half8 a0 = *(const half8*)(Qs + dc * 2560 + (qw * 32 + c) * 40 + q4 * 8);
      const half8 a1 = *(const half8*)(Qs + dc * 2560 + (qw * 32 + 16 + c) * 40 + q4 * 8);
      s[0][0] = MFMA16(a0, kb[0][dc], s[0][0]); s[0][1] = MFMA16(a0, kb[1][dc], s[0][1]);
      s[1][0] = MFMA16(a1, kb[0][dc], s[1][0]); s[1][1] = MFMA16(a1, kb[1][dc], s[1][1]);
    }
    // ---- issue all 16 V b-frag loads NOW (coalesced panel loads) ----
    half8 vb[4][4];
#pragma unroll
    for (int kc = 0; kc < 4; ++kc)
#pragma unroll
      for (int n = 0; n < 4; ++n)
        vb[kc][n] = *(const half8*)(VT + (pt + kc) * 16384 +
                                    (dw + n * 16 + c) * 32 + q4 * 8);
    // ---- local row max over this wave's 32 tok ----
#pragma unroll
    for (int i = 0; i < 2; ++i) {
      fx4 rm;
#pragma unroll
      for (int r = 0; r < 4; ++r) rm[r] = fmaxf(s[i][0][r], s[i][1][r]);
#pragma unroll
      for (int off = 1; off < 16; off <<= 1)
#pragma unroll
        for (int r = 0; r < 4; ++r) rm[r] = fmaxf(rm[r], __shfl_xor(rm[r], off, 64));
      if (c == 0) {
#pragma unroll
        for (int r = 0; r < 4; ++r)
          rmax[tw * 64 + qw * 32 + i * 16 + q4 * 4 + r] = rm[r];
      }
    }
    __syncthreads();
    if (w == 0) {   // lane = q row
      const float mo = mstate[lane];
      float mn = fmaxf(fmaxf(rmax[lane], rmax[64 + lane]),
                       fmaxf(rmax[128 + lane], rmax[192 + lane]));
      mn = fmaxf(mn, mo);
      mnewA[lane]  = mn;
      alphaA[lane] = __expf(mo - mn);
      mstate[lane] = mn;
    }
    __syncthreads();
    // ---- P = exp(s - m) fp16 -> LDS ; l update ; O rescale ----
#pragma unroll
    for (int i = 0; i < 2; ++i)
#pragma unroll
      for (int r = 0; r < 4; ++r) {
        const int q = qw * 32 + i * 16 + q4 * 4 + r;
        const float mn = mnewA[q];
        const float e0 = __expf(s[i][0][r] - mn);
        const float e1 = __expf(s[i][1][r] - mn);
        l_part[i][r] = alphaA[q] * l_part[i][r] + e0 + e1;
        Ps[tw * 2560 + q * 40 + c]      = f2h(e0);
        Ps[tw * 2560 + q * 40 + 16 + c] = f2h(e1);
      }
#pragma unroll
    for (int i4 = 0; i4 < 4; ++i4)
#pragma unroll
      for (int r = 0; r < 4; ++r) {
        const float aq = alphaA[i4 * 16 + q4 * 4 + r];
#pragma unroll
        for (int n = 0; n < 4; ++n) o[i4][n][r] *= aq;
      }
    __syncthreads();
    // ---- PV: a-frags from Ps, V b-frags already in registers ----
#pragma unroll
    for (int kc = 0; kc < 4; ++kc) {
      half8 pa[4];
#pragma unroll
      for (int i4 = 0; i4 < 4; ++i4)
        pa[i4] = *(const half8*)(Ps + kc * 2560 + (i4 * 16 + c) * 40 + q4 * 8);
#pragma unroll
      for (int i4 = 0; i4 < 4; ++i4)
#pragma unroll
        for (int n = 0; n < 4; ++n)
          o[i4][n] = MFMA16(pa[i4], vb[kc][n], o[i4][n]);
    }
  }

  // ---- epilogue: finalize l, normalize, store ----
#pragma unroll
  for (int i = 0; i < 2; ++i) {
    fx4 lv;
#pragma unroll
    for (int r = 0; r < 4; ++r) lv[r] = l_part[i][r];
#pragma unroll
    for (int off = 1; off < 16; off <<= 1)
#pragma unroll
      for (int r = 0; r < 4; ++r) lv[r] += __shfl_xor(lv[r], off, 64);
    if (c == 0) {
#pragma unroll
      for (int r = 0; r < 4; ++r)
        lred[tw * 64 + qw * 32 + i * 16 + q4 * 4 + r] = lv[r];
    }
  }
  __syncthreads();
  if (w == 0)
    alphaA[lane] = 1.0f / (lred[lane] + lred[64 + lane] + lred[128 + lane] + lred[192 + lane]);
  __syncthreads();

  float* ob = out + (tb + q0) * 512 + dw;
#pragma unroll
  for (int i4 = 0; i4 < 4; ++i4)
#pragma unroll
    for (int r = 0; r < 4; ++r) {
      const int q = i4 * 16 + q4 * 4 + r;
      const float li = alphaA[q];
#pragma unroll
      for (int n = 0; n < 4; ++n)
        ob[(long long)q * 512 + n * 16 + c] = o[i4][n][r] * li;
    }
}

// fp32 [R][C] -> fp16 [C][R], two inputs selected by blockIdx.z
__global__ __launch_bounds__(256)
void transpose_cast_w2(const float* __restrict__ in0, const float* __restrict__ in1,
                       ushort* __restrict__ out0, ushort* __restrict__ out1,
                       int R, int C) {
  __shared__ float tile[32][33];
  const float* in  = blockIdx.z ? in1 : in0;
  ushort*      outp = blockIdx.z ? out1 : out0;
  const int c0 = blockIdx.x * 32, r0 = blockIdx.y * 32;
  const int tx = threadIdx.x & 31, ty = threadIdx.x >> 5;
#pragma unroll
  for (int i = 0; i < 32; i += 8)
    tile[ty + i][tx] = in[(long long)(r0 + ty + i) * C + (c0 + tx)];
  __syncthreads();
#pragma unroll
  for (int i = 0; i < 32; i += 8)
    outp[(long long)(c0 + ty + i) * R + (r0 + tx)] = f2h(tile[tx][ty + i]);
}

__global__ __launch_bounds__(256)
void cast_f32_f16(const float* __restrict__ in, ushort* __restrict__ out) {
  const long long i = ((long long)blockIdx.x * 256 + threadIdx.x) * 4;
  const float4 v = *(const float4*)(in + i);
  ushort4 o;
  o.x = f2h(v.x); o.y = f2h(v.y); o.z = f2h(v.z); o.w = f2h(v.w);
  *(ushort4*)(out + i) = o;
}

__global__ __launch_bounds__(256)
void concat_bias(const float* __restrict__ b0, const float* __restrict__ b1,
                 float* __restrict__ out) {
  const int i = blockIdx.x * 256 + threadIdx.x;
  out[i] = (i < 1024) ? b0[i] : b1[i - 1024];
}

extern "C" void kernel_launch(void* const* d_in, const int* in_sizes, int n_in,
                              void* d_out, int out_size, void* d_ws, size_t ws_size,
                              hipStream_t stream) {
  (void)in_sizes; (void)n_in; (void)out_size; (void)ws_size;
  const float* x   = (const float*)d_in[0];
  const float* We1 = (const float*)d_in[1];
  const float* be1 = (const float*)d_in[2];
  const float* We2 = (const float*)d_in[3];
  const float* be2 = (const float*)d_in[4];
  const float* Wk1 = (const float*)d_in[5];
  const float* bk1 = (const float*)d_in[6];
  const float* Wk2 = (const float*)d_in[7];
  const float* bk2 = (const float*)d_in[8];
  float* out = (float*)d_out;
  char* ws = (char*)d_ws;

  ushort* Xb  = (ushort*)(ws + 0);            // 16.78 MB, dead after gemm1
  ushort* W2c = (ushort*)(ws + 0);            // 2 MB, written after gemm1
  ushort* H   = (ushort*)(ws + 16777216);     // 16384x2048 fp16 = 67.1 MB
  ushort* VT  = (ushort*)(ws + 83886080);     // 512 panels x [512 d][32 tok] = 16.78 MB
  ushort* KT  = (ushort*)(ws + 100663296);    // 512 panels x [8 dc][32 tok][32] = 8.39 MB
  ushort* Qm  = (ushort*)(ws + 109051904);    // 16384x256 fp16 = 8.39 MB
  float*  b1c = (float*)(ws + 117440512);     // 2048 fp32
  ushort* W1c = (ushort*)(ws + 117448704);    // 2 MB

  cast_f32_f16<<<dim3(8192), 256, 0, stream>>>(x, Xb);
  transpose_cast_w2<<<dim3(32, 16, 2), 256, 0, stream>>>(We1, Wk1, W1c, W1c + 524288, 512, 1024);
  concat_bias<<<dim3(8), 256, 0, stream>>>(be1, bk1, b1c);

  // H = relu(x @ [We1|Wk1] + [be1|bk1])   [16384,2048]
  gemm_bt<<<dim3(16, 128, 1), 256, 0, stream>>>(Xb, 512, 0, W1c, 512, 0, b1c,
                                                H, 2048, 0, 512, 1 | 2);

  transpose_cast_w2<<<dim3(16, 32, 2), 256, 0, stream>>>(We2, Wk2, W2c, W2c + 524288, 1024, 512);

  // z=0: VT panels ; z=1: KT panels + Qm
  gemm2_pair<<<dim3(4, 128, 2), 256, 0, stream>>>(H, W2c, be2, bk2, VT, KT, Qm);

  // flash attention: grid x=batch (XCD-local), y=64-q tile, 512 thr
  attn_fused<<<dim3(8, 32), 512, 0, stream>>>(KT, VT, Qm, out);
}